// Round 1
// baseline (307.163 us; speedup 1.0000x reference)
//
#include <hip/hip_runtime.h>

// ProtoNet scores: out[n][c] = -sqrt(max(z2 + ||p_c||^2 - 2*z.p_c, 0))
// z = normalize((X - mean) @ proj)
// Strategy: bf16 MFMA for both GEMMs (2% rel tolerance allows it), fused
// normalization in LDS. Prep kernel pre-packs bf16 B-operands in LDS-blob
// layout so the main kernel stages B with pure global_load_lds DMA.

#define DIN    1024
#define DPROJ  256
#define NPROTO 256

#define BM       64
#define BSTRIDE  40                      // ushorts per row (80 B, 16B-aligned, <=2-way banks)
#define BLOB_BYTES (256 * BSTRIDE * 2)   // 20480 B per 32-wide k-tile
#define ZSTRIDE  264                     // 528 B rows, 16B-aligned, 2-way banks

// ws layout
#define PROJT_OFF  0                     // 32 blobs * 20480 = 655360
#define PROTOT_OFF 655360                // 8 blobs * 20480 = 163840
#define MPROJ_OFF  819200                // 256 f32
#define P2_OFF     820224                // 256 f32  (total ws use: 821248 B)

using bf16x8 = __attribute__((ext_vector_type(8))) short;   // 8 bf16 = 4 VGPRs
using f32x4  = __attribute__((ext_vector_type(4))) float;

__device__ __forceinline__ unsigned f2bf(float f) {
  // fp32 -> bf16 round-to-nearest-even, as uint16 in low bits
  unsigned u = __float_as_uint(f);
  return (u + 0x7fffu + ((u >> 16) & 1u)) >> 16;
}

__device__ __forceinline__ void async16(const void* g, void* l) {
  // global -> LDS DMA, 16 B per lane; LDS dest = wave-uniform base + lane*16
  __builtin_amdgcn_global_load_lds(
      (const __attribute__((address_space(1))) unsigned*)g,
      (__attribute__((address_space(3))) unsigned*)l, 16, 0, 0);
}

// ---------------------------------------------------------------------------
// Prep: pack proj^T and prototypes as bf16 LDS-layout blobs; mproj = mean@proj;
// p2[c] = sum_k prototypes[c][k]^2.  48 blocks x 256 threads.
// ---------------------------------------------------------------------------
__global__ __launch_bounds__(256) void protonet_prep(
    const float* __restrict__ mean, const float* __restrict__ proj,
    const float* __restrict__ protos, unsigned short* __restrict__ projT,
    unsigned short* __restrict__ protoT, float* __restrict__ mproj,
    float* __restrict__ p2) {
  const int tid = threadIdx.x;
  const int b = blockIdx.x;
  __shared__ float plds[32 * 257];
  __shared__ float red[256];

  if (b < 32) {
    // ProjT blob kt: blob[n][kk] = bf16(proj[kt*32+kk][n]), row stride 40 (pad=0)
    const int kt = b;
    for (int i = 0; i < 32; ++i) {
      int idx = i * 256 + tid;
      int k = idx >> 8, n = idx & 255;
      plds[k * 257 + n] = proj[(kt * 32 + k) * 256 + n];
    }
    __syncthreads();
    unsigned* dst = (unsigned*)(projT + kt * (BLOB_BYTES / 2));
    for (int i = 0; i < 20; ++i) {
      int d = i * 256 + tid;
      int byte = d * 4;
      int n = byte / 80;
      int rem = byte - n * 80;
      int kk = rem >> 1;
      unsigned lo = (kk < 32) ? f2bf(plds[kk * 257 + n]) : 0u;
      unsigned hi = (kk + 1 < 32) ? f2bf(plds[(kk + 1) * 257 + n]) : 0u;
      dst[d] = lo | (hi << 16);
    }
  } else if (b < 40) {
    // ProtoT blob kt: blob[n][kk] = bf16(protos[n][kt*32+kk])  (no transpose)
    const int kt = b - 32;
    unsigned* dst = (unsigned*)(protoT + kt * (BLOB_BYTES / 2));
    for (int i = 0; i < 20; ++i) {
      int d = i * 256 + tid;
      int byte = d * 4;
      int n = byte / 80;
      int rem = byte - n * 80;
      int kk = rem >> 1;
      unsigned lo = (kk < 32) ? f2bf(protos[n * 256 + kt * 32 + kk]) : 0u;
      unsigned hi = (kk + 1 < 32) ? f2bf(protos[n * 256 + kt * 32 + kk + 1]) : 0u;
      dst[d] = lo | (hi << 16);
    }
  } else if (b < 44) {
    // mproj[n] = sum_k mean[k]*proj[k][n], n-range per block, k split by wave
    const int nb = b - 40;
    const int n = nb * 64 + (tid & 63);
    const int wv = tid >> 6;
    float s = 0.f;
    for (int k = wv * 256; k < wv * 256 + 256; ++k) s += mean[k] * proj[k * 256 + n];
    red[tid] = s;
    __syncthreads();
    if (tid < 64)
      mproj[nb * 64 + tid] = red[tid] + red[tid + 64] + red[tid + 128] + red[tid + 192];
  } else {
    // p2[c] = ||protos[c]||^2, 4 threads per c
    const int cb = b - 44;
    const int c = cb * 64 + (tid >> 2);
    const int qd = tid & 3;
    const float4* pr = (const float4*)(protos + c * 256 + qd * 64);
    float s = 0.f;
#pragma unroll
    for (int i = 0; i < 16; ++i) {
      float4 v = pr[i];
      s += v.x * v.x + v.y * v.y + v.z * v.z + v.w * v.w;
    }
    red[tid] = s;
    __syncthreads();
    if (qd == 0) p2[c] = red[tid] + red[tid + 1] + red[tid + 2] + red[tid + 3];
  }
}

// ---------------------------------------------------------------------------
// Main: 512 blocks x 256 threads, BM=64 rows/block, wave w owns cols [64w,64w+64)
// ---------------------------------------------------------------------------
__global__ __launch_bounds__(256, 2) void protonet_main(
    const float* __restrict__ X, const unsigned short* __restrict__ projT,
    const unsigned short* __restrict__ protoT, const float* __restrict__ mproj,
    const float* __restrict__ p2g, float* __restrict__ out) {
  __shared__ __align__(16) unsigned short Alds[BM * BSTRIDE];     // 5120 B
  __shared__ __align__(16) unsigned short Blds[256 * BSTRIDE];    // 20480 B
  __shared__ __align__(16) unsigned short Zlds[BM * ZSTRIDE];     // 33792 B
  __shared__ float rowsum[BM];
  __shared__ float rowinv[BM];
  __shared__ float rowz2[BM];

  const int tid = threadIdx.x;
  const int wave = tid >> 6;
  const int lane = tid & 63;
  const int l15 = lane & 15;
  const int q = lane >> 4;
  const int row0 = blockIdx.x * BM;
  const int cn = wave * 64;

  if (tid < BM) rowsum[tid] = 0.f;

  // A staging: thread loads rows ar and ar+32, 4 floats each
  const int ar = tid >> 3;
  const int ac4 = (tid & 7) * 4;
  const float* xb = X + (row0 + ar) * DIN + ac4;

  int a_off[4], b_off[4];
#pragma unroll
  for (int mt = 0; mt < 4; ++mt) a_off[mt] = (mt * 16 + l15) * BSTRIDE + q * 8;
#pragma unroll
  for (int nt = 0; nt < 4; ++nt) b_off[nt] = (cn + nt * 16 + l15) * BSTRIDE + q * 8;

  f32x4 acc[4][4];
#pragma unroll
  for (int mt = 0; mt < 4; ++mt)
#pragma unroll
    for (int nt = 0; nt < 4; ++nt) acc[mt][nt] = (f32x4){0.f, 0.f, 0.f, 0.f};

  // ---- GEMM1: Zacc = Xbf16 @ projbf16  (K=1024, 32 steps) ----
  float4 v0 = *(const float4*)(xb);
  float4 v1 = *(const float4*)(xb + 32 * DIN);
  for (int kt = 0; kt < 32; ++kt) {
    // B stage (async DMA of pre-packed blob)
    {
      const char* gsrc = (const char*)projT + kt * BLOB_BYTES;
      char* lbase = (char*)Blds;
#pragma unroll
      for (int i = 0; i < 5; ++i) {
        int off = i * 4096 + wave * 1024;
        async16(gsrc + off + lane * 16, lbase + off);
      }
    }
    // A stage (cvt current prefetched values)
    {
      unsigned pa = f2bf(v0.x) | (f2bf(v0.y) << 16);
      unsigned pb = f2bf(v0.z) | (f2bf(v0.w) << 16);
      unsigned pc = f2bf(v1.x) | (f2bf(v1.y) << 16);
      unsigned pd = f2bf(v1.z) | (f2bf(v1.w) << 16);
      *(uint2*)&Alds[ar * BSTRIDE + ac4] = make_uint2(pa, pb);
      *(uint2*)&Alds[(ar + 32) * BSTRIDE + ac4] = make_uint2(pc, pd);
    }
    __syncthreads();
    // prefetch next X tile while MFMAs run
    if (kt + 1 < 32) {
      v0 = *(const float4*)(xb + (kt + 1) * 32);
      v1 = *(const float4*)(xb + 32 * DIN + (kt + 1) * 32);
    }
    bf16x8 af[4], bfr[4];
#pragma unroll
    for (int mt = 0; mt < 4; ++mt) af[mt] = *(const bf16x8*)&Alds[a_off[mt]];
#pragma unroll
    for (int nt = 0; nt < 4; ++nt) bfr[nt] = *(const bf16x8*)&Blds[b_off[nt]];
#pragma unroll
    for (int mt = 0; mt < 4; ++mt)
#pragma unroll
      for (int nt = 0; nt < 4; ++nt)
        acc[mt][nt] = __builtin_amdgcn_mfma_f32_16x16x32_bf16(af[mt], bfr[nt],
                                                              acc[mt][nt], 0, 0, 0);
    __syncthreads();
  }

  // ---- Epilogue 1: subtract mean@proj, row norms, write normalized bf16 Z ----
  float mp[4];
#pragma unroll
  for (int nt = 0; nt < 4; ++nt) mp[nt] = mproj[cn + nt * 16 + l15];
#pragma unroll
  for (int mt = 0; mt < 4; ++mt)
#pragma unroll
    for (int nt = 0; nt < 4; ++nt)
#pragma unroll
      for (int r = 0; r < 4; ++r) acc[mt][nt][r] -= mp[nt];

#pragma unroll
  for (int mt = 0; mt < 4; ++mt)
#pragma unroll
    for (int r = 0; r < 4; ++r) {
      float ss = 0.f;
#pragma unroll
      for (int nt = 0; nt < 4; ++nt) ss += acc[mt][nt][r] * acc[mt][nt][r];
      ss += __shfl_xor(ss, 1);
      ss += __shfl_xor(ss, 2);
      ss += __shfl_xor(ss, 4);
      ss += __shfl_xor(ss, 8);
      if (l15 == 0) atomicAdd(&rowsum[mt * 16 + q * 4 + r], ss);
    }
  __syncthreads();
  if (tid < BM) {
    float s = rowsum[tid];
    float inv = 1.0f / fmaxf(sqrtf(s), 1e-12f);
    rowinv[tid] = inv;
    rowz2[tid] = s * inv * inv;   // == sum(z_norm^2), matches reference
  }
  __syncthreads();

#pragma unroll
  for (int mt = 0; mt < 4; ++mt)
#pragma unroll
    for (int r = 0; r < 4; ++r) {
      int row = mt * 16 + q * 4 + r;
      float inv = rowinv[row];
#pragma unroll
      for (int nt = 0; nt < 4; ++nt) {
        unsigned bv = f2bf(acc[mt][nt][r] * inv);
        unsigned nb = __shfl_xor((int)bv, 1);
        if ((l15 & 1) == 0) {
          int col = cn + nt * 16 + l15;
          *(unsigned*)&Zlds[row * ZSTRIDE + col] = bv | (nb << 16);
        }
      }
    }

#pragma unroll
  for (int mt = 0; mt < 4; ++mt)
#pragma unroll
    for (int nt = 0; nt < 4; ++nt) acc[mt][nt] = (f32x4){0.f, 0.f, 0.f, 0.f};

  // ---- GEMM2: zp = Zbf16 @ protosbf16^T  (K=256, 8 steps) ----
  for (int kt = 0; kt < 8; ++kt) {
    const char* gsrc = (const char*)protoT + kt * BLOB_BYTES;
    char* lbase = (char*)Blds;
#pragma unroll
    for (int i = 0; i < 5; ++i) {
      int off = i * 4096 + wave * 1024;
      async16(gsrc + off + lane * 16, lbase + off);
    }
    __syncthreads();
    bf16x8 af[4], bfr[4];
#pragma unroll
    for (int mt = 0; mt < 4; ++mt)
      af[mt] = *(const bf16x8*)&Zlds[(mt * 16 + l15) * ZSTRIDE + kt * 32 + q * 8];
#pragma unroll
    for (int nt = 0; nt < 4; ++nt) bfr[nt] = *(const bf16x8*)&Blds[b_off[nt]];
#pragma unroll
    for (int mt = 0; mt < 4; ++mt)
#pragma unroll
      for (int nt = 0; nt < 4; ++nt)
        acc[mt][nt] = __builtin_amdgcn_mfma_f32_16x16x32_bf16(af[mt], bfr[nt],
                                                              acc[mt][nt], 0, 0, 0);
    __syncthreads();
  }

  // ---- Epilogue 2: scores = -sqrt(max(z2 + p2 - 2*zp, 0)) ----
#pragma unroll
  for (int nt = 0; nt < 4; ++nt) {
    int col = cn + nt * 16 + l15;
    float pp = p2g[col];
#pragma unroll
    for (int mt = 0; mt < 4; ++mt)
#pragma unroll
      for (int r = 0; r < 4; ++r) {
        int row = mt * 16 + q * 4 + r;
        float d2 = rowz2[row] + pp - 2.0f * acc[mt][nt][r];
        out[(row0 + row) * NPROTO + col] = -sqrtf(fmaxf(d2, 0.f));
      }
  }
}

extern "C" void kernel_launch(void* const* d_in, const int* in_sizes, int n_in,
                              void* d_out, int out_size, void* d_ws, size_t ws_size,
                              hipStream_t stream) {
  const float* X = (const float*)d_in[0];
  const float* mean = (const float*)d_in[1];
  const float* proj = (const float*)d_in[2];
  const float* protos = (const float*)d_in[3];
  float* out = (float*)d_out;

  char* ws = (char*)d_ws;   // uses 821248 B of workspace
  unsigned short* projT = (unsigned short*)(ws + PROJT_OFF);
  unsigned short* protoT = (unsigned short*)(ws + PROTOT_OFF);
  float* mproj = (float*)(ws + MPROJ_OFF);
  float* p2 = (float*)(ws + P2_OFF);

  hipLaunchKernelGGL(protonet_prep, dim3(48), dim3(256), 0, stream,
                     mean, proj, protos, projT, protoT, mproj, p2);
  hipLaunchKernelGGL(protonet_main, dim3(512), dim3(256), 0, stream,
                     X, projT, protoT, mproj, p2, out);
}

// Round 2
// 274.587 us; speedup vs baseline: 1.1186x; 1.1186x over previous
//
#include <hip/hip_runtime.h>

// ProtoNet scores, single-GEMM formulation:
//   Z = (X - mean) @ proj            (cols 0..255 of Y)
//   U = (X - mean) @ W, W = proj@P^T (cols 256..511 of Y)  [= Z@P^T exactly]
//   inv = 1/max(||Z||,eps); z2 = ||Z||^2 * inv^2
//   out[n][c] = -sqrt(max(z2 + ||p_c||^2 - 2*U[n][c]*inv, 0))
// One fused GEMM Y = Xbf16 @ [proj|W]bf16 (32768 x 1024 x 512), bf16 MFMA.
// Prep packs [proj|W] as bf16 blobs in LDS layout for pure global_load_lds DMA.

#define DIN     1024
#define NPROTO  256
#define BN      512
#define BM      64
#define BSTRIDE 40                       // ushorts/row: 32 k + 8 pad, 80 B, 16B-aligned
#define BLOB_USH (BN * BSTRIDE)          // 20480 ushorts per 32-wide k-tile blob
#define BLOB_BYTES (BLOB_USH * 2)        // 40960 B

// ws layout (bytes); total 1,317,888
#define BBLOB_OFF 0                      // 32 * 40960 = 1310720
#define MVEC_OFF  1310720                // 512 f32: [mean@proj | mean@W]
#define P2_OFF    1312768                // 256 f32
#define MPART_OFF 1313792                // 4*256 f32 partial mproj

using bf16x8 = __attribute__((ext_vector_type(8))) short;
using f32x4  = __attribute__((ext_vector_type(4))) float;

__device__ __forceinline__ unsigned f2bf(float f) {
  unsigned u = __float_as_uint(f);
  return (u + 0x7fffu + ((u >> 16) & 1u)) >> 16;
}

__device__ __forceinline__ void async16(const void* g, void* l) {
  __builtin_amdgcn_global_load_lds(
      (const __attribute__((address_space(1))) unsigned*)g,
      (__attribute__((address_space(3))) unsigned*)l, 16, 0, 0);
}

// ---------------------------------------------------------------------------
// prep1: proj-part blobs (32) + mproj partials (16) + p2 (4) = 52 blocks
// ---------------------------------------------------------------------------
__global__ __launch_bounds__(256) void protonet_prep1(
    const float* __restrict__ mean, const float* __restrict__ proj,
    const float* __restrict__ protos, unsigned short* __restrict__ Bblob,
    float* __restrict__ mpart, float* __restrict__ p2) {
  const int tid = threadIdx.x;
  const int b = blockIdx.x;
  __shared__ float plds[32 * 257];
  __shared__ float red[256];

  if (b < 32) {
    // blob kt rows 0..255: blob[n][kk] = bf16(proj[kt*32+kk][n])
    const int kt = b;
    for (int i = 0; i < 32; ++i) {
      int idx = i * 256 + tid;
      int k = idx >> 8, n = idx & 255;
      plds[k * 257 + n] = proj[(kt * 32 + k) * 256 + n];
    }
    __syncthreads();
    unsigned* dst = (unsigned*)(Bblob + kt * BLOB_USH);
    for (int i = 0; i < 20; ++i) {
      int d = i * 256 + tid;
      int byte = d * 4;
      int n = byte / 80;
      int rem = byte - n * 80;
      int kk = rem >> 1;
      unsigned lo = (kk < 32) ? f2bf(plds[kk * 257 + n]) : 0u;
      unsigned hi = (kk + 1 < 32) ? f2bf(plds[(kk + 1) * 257 + n]) : 0u;
      dst[d] = lo | (hi << 16);
    }
  } else if (b < 48) {
    // mproj partial: mpart[ks][n] = sum_{k in ks-seg} mean[k]*proj[k][n]
    const int ib = b - 32, nb = ib & 3, ks = ib >> 2;
    const int n = nb * 64 + (tid & 63);
    const int k0 = ks * 256 + (tid >> 6) * 64;
    float s = 0.f;
    for (int k = k0; k < k0 + 64; ++k) s += mean[k] * proj[k * 256 + n];
    red[tid] = s;
    __syncthreads();
    if (tid < 64)
      mpart[ks * 256 + nb * 64 + tid] =
          red[tid] + red[tid + 64] + red[tid + 128] + red[tid + 192];
  } else {
    // p2[c] = ||protos[c]||^2
    const int cb = b - 48;
    const int c = cb * 64 + (tid >> 2);
    const int qd = tid & 3;
    const float4* pr = (const float4*)(protos + c * 256 + qd * 64);
    float s = 0.f;
#pragma unroll
    for (int i = 0; i < 16; ++i) {
      float4 v = pr[i];
      s += v.x * v.x + v.y * v.y + v.z * v.z + v.w * v.w;
    }
    red[tid] = s;
    __syncthreads();
    if (qd == 0) p2[c] = red[tid] + red[tid + 1] + red[tid + 2] + red[tid + 3];
  }
}

// ---------------------------------------------------------------------------
// prep2: W = proj@P^T blobs (128 blocks: kt x c-quads) + mproj finalize + mW (1)
// ---------------------------------------------------------------------------
__global__ __launch_bounds__(256) void protonet_prep2(
    const float* __restrict__ proj, const float* __restrict__ protos,
    unsigned short* __restrict__ Bblob, float* __restrict__ mvec,
    const float* __restrict__ mpart) {
  const int tid = threadIdx.x;
  const int b = blockIdx.x;
  __shared__ float plds[32 * 256];
  __shared__ unsigned short Wl[64 * 33];

  if (b < 128) {
    const int kt = b >> 2, c0 = (b & 3) * 64;
    for (int i = 0; i < 32; ++i) {
      int idx = i * 256 + tid;
      int k = idx >> 8, n = idx & 255;
      plds[k * 256 + n] = proj[(kt * 32 + k) * 256 + n];
    }
    __syncthreads();
    const int c = c0 + (tid & 63);
    const int wv = tid >> 6;          // wave owns k = wv*8 .. wv*8+7 (broadcast reads)
    float acc8[8] = {0.f, 0.f, 0.f, 0.f, 0.f, 0.f, 0.f, 0.f};
    const float4* Pr = (const float4*)(protos + c * 256);
    for (int j4 = 0; j4 < 64; ++j4) {
      float4 pv = Pr[j4];
#pragma unroll
      for (int i = 0; i < 8; ++i) {
        const float4 pj = *(const float4*)&plds[(wv * 8 + i) * 256 + j4 * 4];
        acc8[i] += pj.x * pv.x + pj.y * pv.y + pj.z * pv.z + pj.w * pv.w;
      }
    }
#pragma unroll
    for (int i = 0; i < 8; ++i)
      Wl[(c - c0) * 33 + wv * 8 + i] = (unsigned short)f2bf(acc8[i]);
    __syncthreads();
    // copy 64 rows x 32 ushorts into blob rows 256+c0+r
    unsigned* dst = (unsigned*)(Bblob + kt * BLOB_USH);
#pragma unroll
    for (int j = 0; j < 4; ++j) {
      int w = j * 256 + tid, r = w >> 4, u = w & 15;
      unsigned lo = Wl[r * 33 + 2 * u], hi = Wl[r * 33 + 2 * u + 1];
      dst[(256 + c0 + r) * (BSTRIDE / 2) + u] = lo | (hi << 16);
    }
  } else {
    // finalize mproj; then mW[c] = dot(mproj, P[c,:])
    float m = mpart[tid] + mpart[256 + tid] + mpart[512 + tid] + mpart[768 + tid];
    mvec[tid] = m;
    plds[tid] = m;
    __syncthreads();
    const float4* Pr = (const float4*)(protos + tid * 256);
    float acc = 0.f;
    for (int j4 = 0; j4 < 64; ++j4) {
      float4 pv = Pr[j4];
      const float4 mj = *(const float4*)&plds[j4 * 4];
      acc += mj.x * pv.x + mj.y * pv.y + mj.z * pv.z + mj.w * pv.w;
    }
    mvec[256 + tid] = acc;
  }
}

// ---------------------------------------------------------------------------
// main: 512 blocks x 256 thr, BM=64, wave w -> cols [128w,128w+128) of [Z|U]
// ---------------------------------------------------------------------------
__global__ __launch_bounds__(256, 2) void protonet_main(
    const float* __restrict__ X, const unsigned short* __restrict__ Bblob,
    const float* __restrict__ mvec, const float* __restrict__ p2g,
    float* __restrict__ out) {
  __shared__ __align__(16) unsigned short Alds[BM * BSTRIDE];   // 5120 B
  __shared__ __align__(16) unsigned short Blds[BN * BSTRIDE];   // 40960 B
  __shared__ float rowsum[BM];
  __shared__ float rowinv[BM];
  __shared__ float rowz2[BM];

  const int tid = threadIdx.x;
  const int wave = tid >> 6;
  const int lane = tid & 63;
  const int l15 = lane & 15;
  const int q = lane >> 4;
  const int row0 = blockIdx.x * BM;
  const int cn = wave * 128;

  if (tid < BM) rowsum[tid] = 0.f;

  const int ar = tid >> 3;
  const int ac4 = (tid & 7) * 4;
  const float* xb = X + (row0 + ar) * DIN + ac4;

  f32x4 acc[4][8];
#pragma unroll
  for (int mt = 0; mt < 4; ++mt)
#pragma unroll
    for (int nt = 0; nt < 8; ++nt) acc[mt][nt] = (f32x4){0.f, 0.f, 0.f, 0.f};

  // prefetch first X slices, pack immediately to shrink live range
  float4 v0 = *(const float4*)(xb);
  float4 v1 = *(const float4*)(xb + 32 * DIN);
  uint2 a0 = make_uint2(f2bf(v0.x) | (f2bf(v0.y) << 16), f2bf(v0.z) | (f2bf(v0.w) << 16));
  uint2 a1 = make_uint2(f2bf(v1.x) | (f2bf(v1.y) << 16), f2bf(v1.z) | (f2bf(v1.w) << 16));

  for (int kt = 0; kt < 32; ++kt) {
    // B stage: 40960 B blob via async DMA (wave w covers 4 of every 16 KB)
    {
      const char* gsrc = (const char*)Bblob + kt * BLOB_BYTES + wave * 1024 + lane * 16;
      char* lb = (char*)Blds + wave * 1024;
#pragma unroll
      for (int i = 0; i < 10; ++i) async16(gsrc + i * 4096, lb + i * 4096);
    }
    // A stage
    *(uint2*)&Alds[ar * BSTRIDE + ac4] = a0;
    *(uint2*)&Alds[(ar + 32) * BSTRIDE + ac4] = a1;
    __syncthreads();
    if (kt + 1 < 32) {
      float4 w0 = *(const float4*)(xb + (kt + 1) * 32);
      float4 w1 = *(const float4*)(xb + 32 * DIN + (kt + 1) * 32);
      a0 = make_uint2(f2bf(w0.x) | (f2bf(w0.y) << 16), f2bf(w0.z) | (f2bf(w0.w) << 16));
      a1 = make_uint2(f2bf(w1.x) | (f2bf(w1.y) << 16), f2bf(w1.z) | (f2bf(w1.w) << 16));
    }
    bf16x8 af[4];
#pragma unroll
    for (int mt = 0; mt < 4; ++mt)
      af[mt] = *(const bf16x8*)&Alds[(mt * 16 + l15) * BSTRIDE + q * 8];
#pragma unroll
    for (int h = 0; h < 2; ++h) {
      bf16x8 bfr[4];
#pragma unroll
      for (int n = 0; n < 4; ++n)
        bfr[n] = *(const bf16x8*)&Blds[(cn + (h * 4 + n) * 16 + l15) * BSTRIDE + q * 8];
#pragma unroll
      for (int mt = 0; mt < 4; ++mt)
#pragma unroll
        for (int n = 0; n < 4; ++n)
          acc[mt][h * 4 + n] = __builtin_amdgcn_mfma_f32_16x16x32_bf16(
              af[mt], bfr[n], acc[mt][h * 4 + n], 0, 0, 0);
    }
    __syncthreads();
  }

  // ---- epilogue: center, row norms (waves 0-1 hold Z), scores (waves 2-3) ----
#pragma unroll
  for (int nt = 0; nt < 8; ++nt) {
    float mv = mvec[cn + nt * 16 + l15];
#pragma unroll
    for (int mt = 0; mt < 4; ++mt)
#pragma unroll
      for (int r = 0; r < 4; ++r) acc[mt][nt][r] -= mv;
  }

  if (wave < 2) {
#pragma unroll
    for (int mt = 0; mt < 4; ++mt)
#pragma unroll
      for (int r = 0; r < 4; ++r) {
        float ss = 0.f;
#pragma unroll
        for (int nt = 0; nt < 8; ++nt) ss += acc[mt][nt][r] * acc[mt][nt][r];
        ss += __shfl_xor(ss, 1);
        ss += __shfl_xor(ss, 2);
        ss += __shfl_xor(ss, 4);
        ss += __shfl_xor(ss, 8);
        if (l15 == 0) atomicAdd(&rowsum[mt * 16 + q * 4 + r], ss);
      }
  }
  __syncthreads();
  if (tid < BM) {
    float s = rowsum[tid];
    float inv = 1.0f / fmaxf(sqrtf(s), 1e-12f);
    rowinv[tid] = inv;
    rowz2[tid] = s * inv * inv;
  }
  __syncthreads();

  if (wave >= 2) {
#pragma unroll
    for (int nt = 0; nt < 8; ++nt) {
      int col = cn - 256 + nt * 16 + l15;
      float pp = p2g[col];
#pragma unroll
      for (int mt = 0; mt < 4; ++mt)
#pragma unroll
        for (int r = 0; r < 4; ++r) {
          int row = mt * 16 + q * 4 + r;
          float d2 = rowz2[row] + pp - 2.0f * acc[mt][nt][r] * rowinv[row];
          out[(row0 + row) * NPROTO + col] = -sqrtf(fmaxf(d2, 0.f));
        }
    }
  }
}

extern "C" void kernel_launch(void* const* d_in, const int* in_sizes, int n_in,
                              void* d_out, int out_size, void* d_ws, size_t ws_size,
                              hipStream_t stream) {
  const float* X = (const float*)d_in[0];
  const float* mean = (const float*)d_in[1];
  const float* proj = (const float*)d_in[2];
  const float* protos = (const float*)d_in[3];
  float* out = (float*)d_out;

  char* ws = (char*)d_ws;  // uses 1,317,888 B
  unsigned short* Bblob = (unsigned short*)(ws + BBLOB_OFF);
  float* mvec = (float*)(ws + MVEC_OFF);
  float* p2 = (float*)(ws + P2_OFF);
  float* mpart = (float*)(ws + MPART_OFF);

  hipLaunchKernelGGL(protonet_prep1, dim3(52), dim3(256), 0, stream,
                     mean, proj, protos, Bblob, mpart, p2);
  hipLaunchKernelGGL(protonet_prep2, dim3(129), dim3(256), 0, stream,
                     proj, protos, Bblob, mvec, mpart);
  hipLaunchKernelGGL(protonet_main, dim3(512), dim3(256), 0, stream,
                     X, Bblob, mvec, p2, out);
}

// Round 3
// 271.607 us; speedup vs baseline: 1.1309x; 1.0110x over previous
//
#include <hip/hip_runtime.h>

// ProtoNet scores, single-GEMM formulation:
//   Z = (X - mean) @ proj            (cols 0..255 of Y)
//   U = (X - mean) @ W, W = proj@P^T (cols 256..511 of Y)  [= Z@P^T exactly]
//   inv = 1/max(||Z||,eps); z2 = ||Z||^2 * inv^2
//   out[n][c] = -sqrt(max(z2 + ||p_c||^2 - 2*U[n][c]*inv, 0))
//
// R3 structure: B-fragments load global->VGPR directly (blob is L2-resident;
// no wave ever shares B bytes, so LDS staging of B was pure overhead and
// forced a vmcnt(0) barrier drain). Only A is LDS-staged (shared by 4 waves),
// double-buffered, ONE barrier per K-step. X prefetch is 2 steps deep so the
// only in-flight vmem at each barrier has a full step of slack.
//
// B-blob layout: frag for (kt, wave, nt, lane) at byte
//   ((kt*4 + wave)*8 + nt)*1024 + lane*16
// = B^T[col = wave*128 + nt*16 + (lane&15)][k = kt*32 + (lane>>4)*8 .. +7]
// so each 64-lane dwordx4 load is one contiguous 1 KB segment.

#define DIN     1024
#define NPROTO  256
#define BM      64
#define ASTRIDE 40                       // ushorts/row: 32 k + 8 pad (16B-aligned)
#define KT_BYTES 32768                   // 512 cols * 32 k * 2 B per k-tile

// ws layout (bytes); total 1,055,744
#define BBLOB_OFF 0                      // 32 * 32768 = 1048576
#define MVEC_OFF  1048576                // 512 f32: [mean@proj | mean@W]
#define P2_OFF    1050624                // 256 f32
#define MPART_OFF 1051648                // 4*256 f32 partial mproj

using bf16x8 = __attribute__((ext_vector_type(8))) short;
using f32x4  = __attribute__((ext_vector_type(4))) float;

__device__ __forceinline__ unsigned f2bf(float f) {
  unsigned u = __float_as_uint(f);
  return (u + 0x7fffu + ((u >> 16) & 1u)) >> 16;
}

__device__ __forceinline__ uint2 pack4(float4 v) {
  return make_uint2(f2bf(v.x) | (f2bf(v.y) << 16), f2bf(v.z) | (f2bf(v.w) << 16));
}

// ---------------------------------------------------------------------------
// prep1: proj-part of blob (32 blocks) + mproj partials (16) + p2 (4) = 52
// ---------------------------------------------------------------------------
__global__ __launch_bounds__(256) void protonet_prep1(
    const float* __restrict__ mean, const float* __restrict__ proj,
    const float* __restrict__ protos, unsigned* __restrict__ Bblob,
    float* __restrict__ mpart, float* __restrict__ p2) {
  const int tid = threadIdx.x;
  const int b = blockIdx.x;
  __shared__ float plds[32 * 257];
  __shared__ float red[256];

  if (b < 32) {
    const int kt = b;
    for (int i = 0; i < 32; ++i) {
      int idx = i * 256 + tid;
      int k = idx >> 8, n = idx & 255;
      plds[k * 257 + n] = proj[(kt * 32 + k) * 256 + n];
    }
    __syncthreads();
    // write w in {0,1}: 2*8*64*4 = 4096 uints
    for (int i = 0; i < 16; ++i) {
      int idx = i * 256 + tid;
      int j = idx & 3, lane = (idx >> 2) & 63, nt = (idx >> 8) & 7, w = idx >> 11;
      int l15 = lane & 15, q = lane >> 4;
      int col = w * 128 + nt * 16 + l15;
      int kk = q * 8 + 2 * j;
      unsigned lo = f2bf(plds[kk * 257 + col]);
      unsigned hi = f2bf(plds[(kk + 1) * 257 + col]);
      Bblob[((kt * 4 + w) * 8 + nt) * 256 + lane * 4 + j] = lo | (hi << 16);
    }
  } else if (b < 48) {
    const int ib = b - 32, nb = ib & 3, ks = ib >> 2;
    const int n = nb * 64 + (tid & 63);
    const int k0 = ks * 256 + (tid >> 6) * 64;
    float s = 0.f;
    for (int k = k0; k < k0 + 64; ++k) s += mean[k] * proj[k * 256 + n];
    red[tid] = s;
    __syncthreads();
    if (tid < 64)
      mpart[ks * 256 + nb * 64 + tid] =
          red[tid] + red[tid + 64] + red[tid + 128] + red[tid + 192];
  } else {
    const int cb = b - 48;
    const int c = cb * 64 + (tid >> 2);
    const int qd = tid & 3;
    const float4* pr = (const float4*)(protos + c * 256 + qd * 64);
    float s = 0.f;
#pragma unroll
    for (int i = 0; i < 16; ++i) {
      float4 v = pr[i];
      s += v.x * v.x + v.y * v.y + v.z * v.z + v.w * v.w;
    }
    red[tid] = s;
    __syncthreads();
    if (qd == 0) p2[c] = red[tid] + red[tid + 1] + red[tid + 2] + red[tid + 3];
  }
}

// ---------------------------------------------------------------------------
// prep2: W = proj@P^T into blob (128 blocks) + mproj finalize + mW (1) = 129
// ---------------------------------------------------------------------------
__global__ __launch_bounds__(256) void protonet_prep2(
    const float* __restrict__ proj, const float* __restrict__ protos,
    unsigned* __restrict__ Bblob, float* __restrict__ mvec,
    const float* __restrict__ mpart) {
  const int tid = threadIdx.x;
  const int b = blockIdx.x;
  __shared__ float plds[32 * 256];
  __shared__ unsigned short Wl[64 * 33];

  if (b < 128) {
    const int kt = b >> 2, c0 = (b & 3) * 64;
    for (int i = 0; i < 32; ++i) {
      int idx = i * 256 + tid;
      int k = idx >> 8, n = idx & 255;
      plds[k * 256 + n] = proj[(kt * 32 + k) * 256 + n];
    }
    __syncthreads();
    const int c = c0 + (tid & 63);
    const int wv = tid >> 6;
    float acc8[8] = {0.f, 0.f, 0.f, 0.f, 0.f, 0.f, 0.f, 0.f};
    const float4* Pr = (const float4*)(protos + c * 256);
    for (int j4 = 0; j4 < 64; ++j4) {
      float4 pv = Pr[j4];
#pragma unroll
      for (int i = 0; i < 8; ++i) {
        const float4 pj = *(const float4*)&plds[(wv * 8 + i) * 256 + j4 * 4];
        acc8[i] += pj.x * pv.x + pj.y * pv.y + pj.z * pv.z + pj.w * pv.w;
      }
    }
#pragma unroll
    for (int i = 0; i < 8; ++i)
      Wl[(c - c0) * 33 + wv * 8 + i] = (unsigned short)f2bf(acc8[i]);
    __syncthreads();
    // scatter 64 cols x 32 k into blob (global col = 256 + c0 + r)
    for (int i = 0; i < 4; ++i) {
      int idx = i * 256 + tid;
      int j = idx & 3, q = (idx >> 2) & 3, r = idx >> 4;
      int gc = c0 + r;                  // 0..255 within W block
      int w = 2 + (gc >> 7);
      int cw = gc & 127;
      int nt = cw >> 4, l15 = cw & 15;
      int lane = q * 16 + l15;
      int kk = q * 8 + 2 * j;
      unsigned lo = Wl[r * 33 + kk], hi = Wl[r * 33 + kk + 1];
      Bblob[((kt * 4 + w) * 8 + nt) * 256 + lane * 4 + j] = lo | (hi << 16);
    }
  } else {
    float m = mpart[tid] + mpart[256 + tid] + mpart[512 + tid] + mpart[768 + tid];
    mvec[tid] = m;
    plds[tid] = m;
    __syncthreads();
    const float4* Pr = (const float4*)(protos + tid * 256);
    float acc = 0.f;
    for (int j4 = 0; j4 < 64; ++j4) {
      float4 pv = Pr[j4];
      const float4 mj = *(const float4*)&plds[j4 * 4];
      acc += mj.x * pv.x + mj.y * pv.y + mj.z * pv.z + mj.w * pv.w;
    }
    mvec[256 + tid] = acc;
  }
}

// ---------------------------------------------------------------------------
// main: 512 blocks x 256 thr, BM=64; wave w -> cols [128w,128w+128) of [Z|U].
// B: global->VGPR (L2-hot blob). A: LDS double-buffer, ONE barrier per step.
// ---------------------------------------------------------------------------
__global__ __launch_bounds__(256, 2) void protonet_main(
    const float* __restrict__ X, const unsigned* __restrict__ Bblob,
    const float* __restrict__ mvec, const float* __restrict__ p2g,
    float* __restrict__ out) {
  __shared__ __align__(16) unsigned short Alds[2][BM * ASTRIDE];  // 2 x 5120 B
  __shared__ float rowsum[BM];
  __shared__ float rowinv[BM];
  __shared__ float rowz2[BM];

  const int tid = threadIdx.x;
  const int wave = tid >> 6;
  const int lane = tid & 63;
  const int l15 = lane & 15;
  const int q = lane >> 4;
  const int row0 = blockIdx.x * BM;
  const int cn = wave * 128;

  if (tid < BM) rowsum[tid] = 0.f;

  const int ar = tid >> 3;
  const int ac4 = (tid & 7) * 4;
  const float* xb = X + (row0 + ar) * DIN + ac4;
  const char* Bb = (const char*)Bblob + wave * 8192 + lane * 16;

  f32x4 acc[4][8];
#pragma unroll
  for (int mt = 0; mt < 4; ++mt)
#pragma unroll
    for (int nt = 0; nt < 8; ++nt) acc[mt][nt] = (f32x4){0.f, 0.f, 0.f, 0.f};

  // prologue: stage A(0), prefetch X(1)
  float4 p0 = *(const float4*)(xb);
  float4 p1 = *(const float4*)(xb + 32 * DIN);
  *(uint2*)&Alds[0][ar * ASTRIDE + ac4] = pack4(p0);
  *(uint2*)&Alds[0][(ar + 32) * ASTRIDE + ac4] = pack4(p1);
  p0 = *(const float4*)(xb + 32);
  p1 = *(const float4*)(xb + 32 * DIN + 32);
  __syncthreads();

  for (int kt = 0; kt < 32; ++kt) {
    // X prefetch for kt+2 (full step of slack before the barrier drains it)
    float4 n0 = p0, n1 = p1;
    if (kt + 2 < 32) {
      n0 = *(const float4*)(xb + (kt + 2) * 32);
      n1 = *(const float4*)(xb + 32 * DIN + (kt + 2) * 32);
    }
    // B fragments straight from global (L2-hot), contiguous 1 KB per load
    const char* bs = Bb + kt * KT_BYTES;
    bf16x8 bfr[8];
#pragma unroll
    for (int nt = 0; nt < 8; ++nt) bfr[nt] = *(const bf16x8*)(bs + nt * 1024);
    // A fragments from current LDS buffer
    bf16x8 af[4];
#pragma unroll
    for (int mt = 0; mt < 4; ++mt)
      af[mt] = *(const bf16x8*)&Alds[kt & 1][(mt * 16 + l15) * ASTRIDE + q * 8];
    // stage A(kt+1) into the other buffer (uses X prefetched at kt-1)
    if (kt + 1 < 32) {
      *(uint2*)&Alds[(kt + 1) & 1][ar * ASTRIDE + ac4] = pack4(p0);
      *(uint2*)&Alds[(kt + 1) & 1][(ar + 32) * ASTRIDE + ac4] = pack4(p1);
    }
#pragma unroll
    for (int mt = 0; mt < 4; ++mt)
#pragma unroll
      for (int nt = 0; nt < 8; ++nt)
        acc[mt][nt] = __builtin_amdgcn_mfma_f32_16x16x32_bf16(af[mt], bfr[nt],
                                                              acc[mt][nt], 0, 0, 0);
    p0 = n0;
    p1 = n1;
    __syncthreads();
  }

  // ---- epilogue: center, row norms (waves 0-1 hold Z), scores (waves 2-3) ----
#pragma unroll
  for (int nt = 0; nt < 8; ++nt) {
    float mv = mvec[cn + nt * 16 + l15];
#pragma unroll
    for (int mt = 0; mt < 4; ++mt)
#pragma unroll
      for (int r = 0; r < 4; ++r) acc[mt][nt][r] -= mv;
  }

  if (wave < 2) {
#pragma unroll
    for (int mt = 0; mt < 4; ++mt)
#pragma unroll
      for (int r = 0; r < 4; ++r) {
        float ss = 0.f;
#pragma unroll
        for (int nt = 0; nt < 8; ++nt) ss += acc[mt][nt][r] * acc[mt][nt][r];
        ss += __shfl_xor(ss, 1);
        ss += __shfl_xor(ss, 2);
        ss += __shfl_xor(ss, 4);
        ss += __shfl_xor(ss, 8);
        if (l15 == 0) atomicAdd(&rowsum[mt * 16 + q * 4 + r], ss);
      }
  }
  __syncthreads();
  if (tid < BM) {
    float s = rowsum[tid];
    float inv = 1.0f / fmaxf(sqrtf(s), 1e-12f);
    rowinv[tid] = inv;
    rowz2[tid] = s * inv * inv;
  }
  __syncthreads();

  if (wave >= 2) {
#pragma unroll
    for (int nt = 0; nt < 8; ++nt) {
      int col = cn - 256 + nt * 16 + l15;
      float pp = p2g[col];
#pragma unroll
      for (int mt = 0; mt < 4; ++mt)
#pragma unroll
        for (int r = 0; r < 4; ++r) {
          int row = mt * 16 + q * 4 + r;
          float d2 = rowz2[row] + pp - 2.0f * acc[mt][nt][r] * rowinv[row];
          out[(row0 + row) * NPROTO + col] = -sqrtf(fmaxf(d2, 0.f));
        }
    }
  }
}

extern "C" void kernel_launch(void* const* d_in, const int* in_sizes, int n_in,
                              void* d_out, int out_size, void* d_ws, size_t ws_size,
                              hipStream_t stream) {
  const float* X = (const float*)d_in[0];
  const float* mean = (const float*)d_in[1];
  const float* proj = (const float*)d_in[2];
  const float* protos = (const float*)d_in[3];
  float* out = (float*)d_out;

  char* ws = (char*)d_ws;  // uses 1,055,744 B
  unsigned* Bblob = (unsigned*)(ws + BBLOB_OFF);
  float* mvec = (float*)(ws + MVEC_OFF);
  float* p2 = (float*)(ws + P2_OFF);
  float* mpart = (float*)(ws + MPART_OFF);

  hipLaunchKernelGGL(protonet_prep1, dim3(52), dim3(256), 0, stream,
                     mean, proj, protos, Bblob, mpart, p2);
  hipLaunchKernelGGL(protonet_prep2, dim3(129), dim3(256), 0, stream,
                     proj, protos, Bblob, mvec, mpart);
  hipLaunchKernelGGL(protonet_main, dim3(512), dim3(256), 0, stream,
                     X, Bblob, mvec, p2, out);
}